// Round 2
// baseline (1274.376 us; speedup 1.0000x reference)
//
#include <hip/hip_runtime.h>

#define HIN 192
#define WOUT 384
#define NIN 32
#define NOUT 16
#define NSLOT 9

// output tile 32x16 -> 16x8 sites (site = 2x2 output parity group)
#define OTW 32
#define OTH 16
#define SXN 16
#define SYN 8
#define ITW 18
#define ITH 10
#define NPX (ITW * ITH)   // 180

__device__ __forceinline__ unsigned short f2bf(float f) {
    union { float f; unsigned int u; } v; v.f = f;
    unsigned int r = v.u + 0x7fffu + ((v.u >> 16) & 1u);   // RNE
    return (unsigned short)(r >> 16);
}
__device__ __forceinline__ float bfl(unsigned int u) { return __uint_as_float(u << 16); }
__device__ __forceinline__ float bfh(unsigned int u) { return __uint_as_float(u & 0xffff0000u); }

__global__ __launch_bounds__(256, 2) void steered_fused(
    const float* __restrict__ x,       // (8,32,192,192)
    const float* __restrict__ alpha,   // (2,8,1,384,384)
    const float* __restrict__ weights, // (16,32,9)
    const float* __restrict__ bias,    // (16,)
    float* __restrict__ out)           // (8,16,384,384)
{
    // LDS: W remapped [i][m], m = s*16+o (18432 B); h tile bf16 [s][px][o] (51840 B);
    // basis coef pairs (Cr,Ci) per slot/kernel-pos (1800 B). Total 72072 B -> 2 blocks/CU.
    __shared__ float Wl[NIN][NSLOT * NOUT];
    __shared__ __align__(16) unsigned short hl[NSLOT][NPX][NOUT];
    __shared__ float2 Cb[NSLOT][25];

    // ---- build basis coefficient table ----
    for (int q = threadIdx.x; q < NSLOT * 25; q += 256) {
        int s = q / 25, p = q % 25;
        int ky = p / 5, kx = p % 5;
        float ys = (float)(ky - 2), xs = (float)(kx - 2);
        float r = sqrtf(xs * xs + ys * ys);
        float th = atan2f(ys, xs);
        float cr, ci;
        if (s < 3) {
            float d = r - (float)s;
            cr = expf(-d * d * (1.0f / 0.72f));
            ci = 0.0f;
        } else {
            int k = (s - 3) / 2 + 1;
            float r0 = ((s - 3) & 1) ? 2.0f : 1.0f;
            float d = r - r0;
            float ring = expf(-d * d * (1.0f / 0.72f));
            float a = (float)k * th;
            cr = ring * cosf(a);
            ci = ring * sinf(a);
        }
        Cb[s][p] = make_float2(cr, ci);
    }
    // ---- load W into LDS, m = s*16+o ----
    for (int q = threadIdx.x; q < NIN * NSLOT * NOUT; q += 256) {
        int i = q / (NSLOT * NOUT), m = q % (NSLOT * NOUT);
        int s = m / 16, o = m % 16;
        Wl[i][m] = weights[(o * NIN + i) * NSLOT + s];
    }
    __syncthreads();

    const int n = blockIdx.z;
    const int OYB = blockIdx.y * OTH, OXB = blockIdx.x * OTW;
    const int IYB = OYB >> 1, IXB = OXB >> 1;

    // ================= stage 1: h[s][px][o] = sum_i W * x =================
    if (threadIdx.x < NPX) {
        const int q = threadIdx.x;
        const int lrow = q / ITW, lcol = q % ITW;
        const int iy = IYB - 1 + lrow, ix = IXB - 1 + lcol;
        const bool inimg = (iy >= 0) && (iy < HIN) && (ix >= 0) && (ix < HIN);
        float xv[NIN];
        if (inimg) {
            const float* xp = x + (size_t)n * NIN * HIN * HIN + iy * HIN + ix;
            #pragma unroll
            for (int i = 0; i < NIN; ++i) xv[i] = xp[i * HIN * HIN];
        } else {
            #pragma unroll
            for (int i = 0; i < NIN; ++i) xv[i] = 0.0f;
        }
        #pragma unroll 1
        for (int c = 0; c < 18; ++c) {          // chunk = 8 consecutive m (same slot, o-half)
            float a[8];
            #pragma unroll
            for (int j = 0; j < 8; ++j) a[j] = 0.0f;
            #pragma unroll
            for (int i = 0; i < NIN; ++i) {
                const float xi = xv[i];
                #pragma unroll
                for (int j = 0; j < 8; ++j)
                    a[j] = fmaf(Wl[i][c * 8 + j], xi, a[j]);   // wave-uniform -> broadcast b128
            }
            unsigned int pk[4];
            #pragma unroll
            for (int j = 0; j < 4; ++j)
                pk[j] = (unsigned int)f2bf(a[2 * j]) | ((unsigned int)f2bf(a[2 * j + 1]) << 16);
            uint4 v; v.x = pk[0]; v.y = pk[1]; v.z = pk[2]; v.w = pk[3];
            *reinterpret_cast<uint4*>(&hl[c >> 1][q][(c & 1) * 8]) = v;
        }
    }
    __syncthreads();

    // ================= stage 2: per-site tap dots =================
    const int tid = threadIdx.x;
    const int oh = tid & 1;                 // o-half
    const int sx = (tid >> 1) & 15;
    const int sy = tid >> 5;
    const int Y = IYB + sy, X = IXB + sx;

    // angular coefficients + rho for the 4 parity pixels of this site
    float cc[3][4], ssv[3][4], rho[4];
    #pragma unroll
    for (int p = 0; p < 4; ++p) {
        int py = p >> 1, qx = p & 1;
        int oy = 2 * Y + py, ox = 2 * X + qx;
        int aoff = (n * WOUT + oy) * WOUT + ox;
        float a0 = alpha[aoff];
        float a1 = alpha[(size_t)8 * WOUT * WOUT + aoff];
        float rr = sqrtf(a0 * a0 + a1 * a1);
        rho[p] = rr;
        float inv = 1.0f / (rr + 1e-8f);
        float c = a0 * inv, s_ = a1 * inv;
        cc[0][p] = c;                          ssv[0][p] = s_;
        cc[1][p] = c * c - s_ * s_;            ssv[1][p] = 2.0f * c * s_;
        cc[2][p] = cc[1][p] * c - ssv[1][p] * s_;
        ssv[2][p] = ssv[1][p] * c + cc[1][p] * s_;
    }

    float acc[4][8];
    #pragma unroll
    for (int p = 0; p < 4; ++p)
        #pragma unroll
        for (int j = 0; j < 8; ++j) acc[p][j] = 0.0f;

    const int baseq = (sy + 2) * ITW + (sx + 2);

    #pragma unroll
    for (int s = 0; s < NSLOT; ++s) {
        #pragma unroll
        for (int ty = 0; ty < 3; ++ty) {
            #pragma unroll
            for (int tx = 0; tx < 3; ++tx) {
                const int q = baseq - ty * ITW - tx;
                const uint4 w4 = *reinterpret_cast<const uint4*>(&hl[s][q][oh * 8]);
                float hv[8];
                hv[0] = bfl(w4.x); hv[1] = bfh(w4.x);
                hv[2] = bfl(w4.y); hv[3] = bfh(w4.y);
                hv[4] = bfl(w4.z); hv[5] = bfh(w4.z);
                hv[6] = bfl(w4.w); hv[7] = bfh(w4.w);
                #pragma unroll
                for (int p = 0; p < 4; ++p) {
                    const int py = p >> 1, qx = p & 1;
                    if ((ty == 2 && py == 1) || (tx == 2 && qx == 1)) continue; // ky/kx > 4
                    const int bi = (py + 2 * ty) * 5 + (qx + 2 * tx);
                    const float2 C = Cb[s][bi];
                    float eb;
                    if (s < 3) {
                        eb = C.x;
                    } else {
                        const int k = (s - 3) >> 1;       // constant-folded after unroll
                        eb = C.x * cc[k][p] + C.y * ssv[k][p];
                    }
                    #pragma unroll
                    for (int j = 0; j < 8; ++j)
                        acc[p][j] = fmaf(eb, hv[j], acc[p][j]);
                }
            }
        }
    }

    // ---- epilogue: rho*acc + bias, paired stores over x-parity ----
    float bv[8];
    #pragma unroll
    for (int j = 0; j < 8; ++j) bv[j] = bias[oh * 8 + j];

    #pragma unroll
    for (int py = 0; py < 2; ++py) {
        const int oy = 2 * Y + py;
        #pragma unroll
        for (int j = 0; j < 8; ++j) {
            const int o = oh * 8 + j;
            float2 v;
            v.x = rho[py * 2 + 0] * acc[py * 2 + 0][j] + bv[j];
            v.y = rho[py * 2 + 1] * acc[py * 2 + 1][j] + bv[j];
            *reinterpret_cast<float2*>(
                &out[(((size_t)n * NOUT + o) * WOUT + oy) * WOUT + 2 * X]) = v;
        }
    }
}

extern "C" void kernel_launch(void* const* d_in, const int* in_sizes, int n_in,
                              void* d_out, int out_size, void* d_ws, size_t ws_size,
                              hipStream_t stream) {
    const float* x       = (const float*)d_in[0];
    const float* alpha   = (const float*)d_in[1];
    const float* weights = (const float*)d_in[2];
    const float* bias    = (const float*)d_in[3];
    float* out = (float*)d_out;

    dim3 grid(WOUT / OTW, WOUT / OTH, 8);   // 12 x 24 x 8 = 2304 blocks
    steered_fused<<<grid, 256, 0, stream>>>(x, alpha, weights, bias, out);
}

// Round 3
// 1001.562 us; speedup vs baseline: 1.2724x; 1.2724x over previous
//
#include <hip/hip_runtime.h>

#define HIN 192
#define WOUT 384
#define NIN 32
#define NOUT 16
#define NSLOT 9
#define NM 144                    // 9 slots * 16 out-channels
#define HP 194                    // padded input dim (1-px halo)
#define HPLANE (HP * HP)          // 37636
#define HBATCH ((size_t)HPLANE * NM)   // h elems per batch (bf16)

typedef unsigned short ushort_t;

__device__ __forceinline__ unsigned short f2bf(float f) {
    union { float f; unsigned int u; } v; v.f = f;
    unsigned int r = v.u + 0x7fffu + ((v.u >> 16) & 1u);   // RNE
    return (unsigned short)(r >> 16);
}
__device__ __forceinline__ float bfl(unsigned int u) { return __uint_as_float(u << 16); }
__device__ __forceinline__ float bfh(unsigned int u) { return __uint_as_float(u & 0xffff0000u); }

// ---------------- prep: Wt[c*256 + i*8 + j] = W[o][i][s],  m=c*8+j, s=m>>4, o=m&15 ----------------
__global__ __launch_bounds__(256) void kprep_w(const float* __restrict__ w, float* __restrict__ Wt) {
    int t = blockIdx.x * 256 + threadIdx.x;
    if (t >= NIN * NM) return;            // 4608
    int c = t >> 8, r = t & 255;
    int i = r >> 3, j = r & 7;
    int m = c * 8 + j;
    int s = m >> 4, o = m & 15;
    Wt[t] = w[(o * NIN + i) * NSLOT + s];
}

// ---------------- zero the 1-px halo border of h for nb batches ----------------
__global__ __launch_bounds__(256) void kzero(ushort_t* __restrict__ h, int nb) {
    int t = blockIdx.x * 256 + threadIdx.x;
    if (t >= nb * 772) return;
    int b = t / 772, r = t % 772;
    int iy, ix;
    if (r < 194)      { iy = 0;           ix = r; }
    else if (r < 388) { iy = 193;         ix = r - 194; }
    else if (r < 580) { iy = r - 388 + 1; ix = 0; }
    else              { iy = r - 580 + 1; ix = 193; }
    ushort_t* p = h + (size_t)b * HBATCH + ((size_t)iy * HP + ix) * NM;
    uint4 z; z.x = 0; z.y = 0; z.z = 0; z.w = 0;
    #pragma unroll
    for (int c = 0; c < 18; ++c) reinterpret_cast<uint4*>(p)[c] = z;
}

// ---------------- kA: h[b][iy+1][ix+1][m] = bf16( sum_i Wt * x ) ----------------
__global__ __launch_bounds__(256) void kA(const float* __restrict__ x,
                                          const float* __restrict__ Wt,
                                          ushort_t* __restrict__ h, int n0) {
    const int b = blockIdx.y;
    const int n = n0 + b;
    const int px = blockIdx.x * 256 + threadIdx.x;   // 0..36863
    const int iy = px / HIN, ix = px % HIN;
    const float* xp = x + (size_t)n * NIN * HIN * HIN + px;
    float xv[NIN];
    #pragma unroll
    for (int i = 0; i < NIN; ++i) xv[i] = xp[(size_t)i * HIN * HIN];
    ushort_t* hp = h + (size_t)b * HBATCH + ((size_t)(iy + 1) * HP + (ix + 1)) * NM;
    #pragma unroll 1
    for (int c = 0; c < 18; ++c) {
        const float* wc = Wt + c * 256;              // block-uniform -> s_loads
        float a[8];
        #pragma unroll
        for (int j = 0; j < 8; ++j) a[j] = 0.0f;
        #pragma unroll
        for (int i = 0; i < NIN; ++i) {
            const float xi = xv[i];
            #pragma unroll
            for (int j = 0; j < 8; ++j) a[j] = fmaf(wc[i * 8 + j], xi, a[j]);
        }
        uint4 v;
        v.x = (unsigned)f2bf(a[0]) | ((unsigned)f2bf(a[1]) << 16);
        v.y = (unsigned)f2bf(a[2]) | ((unsigned)f2bf(a[3]) << 16);
        v.z = (unsigned)f2bf(a[4]) | ((unsigned)f2bf(a[5]) << 16);
        v.w = (unsigned)f2bf(a[6]) | ((unsigned)f2bf(a[7]) << 16);
        *reinterpret_cast<uint4*>(hp + c * 8) = v;
    }
}

// ---------------- kB: per-site tap dots (compile-time slot S) ----------------
template<int S>
__device__ __forceinline__ void do_slot(const ushort_t* __restrict__ hb,
                                        const float2 (&Cb)[NSLOT][25],
                                        const float (&cc)[3][4], const float (&ss)[3][4],
                                        float (&acc)[4][8],
                                        const int (&r_)[3], const int (&c_)[3]) {
    #pragma unroll
    for (int ty = 0; ty < 3; ++ty) {
        #pragma unroll
        for (int tx = 0; tx < 3; ++tx) {
            const uint4 v = *reinterpret_cast<const uint4*>(hb + r_[ty] + c_[tx] + S * 16);
            float hv[8];
            hv[0] = bfl(v.x); hv[1] = bfh(v.x);
            hv[2] = bfl(v.y); hv[3] = bfh(v.y);
            hv[4] = bfl(v.z); hv[5] = bfh(v.z);
            hv[6] = bfl(v.w); hv[7] = bfh(v.w);
            #pragma unroll
            for (int p = 0; p < 4; ++p) {
                const int py = p >> 1, qx = p & 1;
                if ((ty == 2 && py == 1) || (tx == 2 && qx == 1)) continue;  // ky/kx > 4
                const int bi = (py + 2 * ty) * 5 + (qx + 2 * tx);
                const float2 C = Cb[S][bi];
                float eb;
                if (S < 3) {
                    eb = C.x;
                } else {
                    const int k = (S - 3) >> 1;       // compile-time
                    eb = C.x * cc[k][p] + C.y * ss[k][p];
                }
                #pragma unroll
                for (int j = 0; j < 8; ++j) acc[p][j] = fmaf(eb, hv[j], acc[p][j]);
            }
        }
    }
}

__global__ __launch_bounds__(256) void kB(const ushort_t* __restrict__ h,
                                          const float* __restrict__ alpha,
                                          const float* __restrict__ bias,
                                          float* __restrict__ out, int n0) {
    __shared__ float2 Cb[NSLOT][25];
    {
        int q = threadIdx.x;
        if (q < NSLOT * 25) {
            int s = q / 25, p = q % 25;
            int ky = p / 5, kx = p % 5;
            float ys = (float)(ky - 2), xs = (float)(kx - 2);
            float r = sqrtf(xs * xs + ys * ys);
            float th = atan2f(ys, xs);
            float cr, ci;
            if (s < 3) {
                float d = r - (float)s;
                cr = expf(-d * d * (1.0f / 0.72f));
                ci = 0.0f;
            } else {
                int k = (s - 3) / 2 + 1;
                float r0 = ((s - 3) & 1) ? 2.0f : 1.0f;
                float d = r - r0;
                float ring = expf(-d * d * (1.0f / 0.72f));
                float a = (float)k * th;
                cr = ring * cosf(a);
                ci = ring * sinf(a);
            }
            Cb[s][p] = make_float2(cr, ci);
        }
    }
    __syncthreads();

    const int b = blockIdx.z;
    const int n = n0 + b;
    const int tid = threadIdx.x;
    const int oh = tid & 1;
    const int sx = (tid >> 1) & 15;
    const int sy = tid >> 5;
    const int Y = blockIdx.y * 8 + sy;
    const int X = blockIdx.x * 16 + sx;

    float cc[3][4], ss[3][4], rho[4];
    #pragma unroll
    for (int p = 0; p < 4; ++p) {
        const int py = p >> 1, qx = p & 1;
        const int oy = 2 * Y + py, ox = 2 * X + qx;
        const int aoff = (n * WOUT + oy) * WOUT + ox;
        float a0 = alpha[aoff];
        float a1 = alpha[(size_t)8 * WOUT * WOUT + aoff];
        float rr = sqrtf(a0 * a0 + a1 * a1);
        rho[p] = rr;
        float inv = 1.0f / (rr + 1e-8f);
        float c = a0 * inv, s_ = a1 * inv;
        cc[0][p] = c;                       ss[0][p] = s_;
        cc[1][p] = c * c - s_ * s_;         ss[1][p] = 2.0f * c * s_;
        cc[2][p] = cc[1][p] * c - ss[1][p] * s_;
        ss[2][p] = ss[1][p] * c + cc[1][p] * s_;
    }

    float acc[4][8];
    #pragma unroll
    for (int p = 0; p < 4; ++p)
        #pragma unroll
        for (int j = 0; j < 8; ++j) acc[p][j] = 0.0f;

    const ushort_t* hb = h + (size_t)b * HBATCH + oh * 8;
    int r_[3], c_[3];
    #pragma unroll
    for (int t = 0; t < 3; ++t) {
        r_[t] = (Y + 2 - t) * HP * NM;
        c_[t] = (X + 2 - t) * NM;
    }

    do_slot<0>(hb, Cb, cc, ss, acc, r_, c_);
    do_slot<1>(hb, Cb, cc, ss, acc, r_, c_);
    do_slot<2>(hb, Cb, cc, ss, acc, r_, c_);
    do_slot<3>(hb, Cb, cc, ss, acc, r_, c_);
    do_slot<4>(hb, Cb, cc, ss, acc, r_, c_);
    do_slot<5>(hb, Cb, cc, ss, acc, r_, c_);
    do_slot<6>(hb, Cb, cc, ss, acc, r_, c_);
    do_slot<7>(hb, Cb, cc, ss, acc, r_, c_);
    do_slot<8>(hb, Cb, cc, ss, acc, r_, c_);

    float bv[8];
    #pragma unroll
    for (int j = 0; j < 8; ++j) bv[j] = bias[oh * 8 + j];

    #pragma unroll
    for (int py = 0; py < 2; ++py) {
        const int oy = 2 * Y + py;
        #pragma unroll
        for (int j = 0; j < 8; ++j) {
            const int o = oh * 8 + j;
            float2 v;
            v.x = rho[py * 2 + 0] * acc[py * 2 + 0][j] + bv[j];
            v.y = rho[py * 2 + 1] * acc[py * 2 + 1][j] + bv[j];
            *reinterpret_cast<float2*>(
                &out[(((size_t)n * NOUT + o) * WOUT + oy) * WOUT + 2 * X]) = v;
        }
    }
}

// ---------------- fallback: proven round-1 kernel (no workspace needed) ----------------
__global__ __launch_bounds__(256) void steered_convT(
    const float* __restrict__ x, const float* __restrict__ alpha,
    const float* __restrict__ weights, const float* __restrict__ bias,
    float* __restrict__ out) {
    __shared__ float sb[15 * 25];
    for (int q = threadIdx.x; q < 375; q += 256) {
        int s = q / 25, p = q % 25;
        int ky = p / 5, kx = p % 5;
        float ys = (float)(ky - 2), xs = (float)(kx - 2);
        float r = sqrtf(xs * xs + ys * ys);
        float th = atan2f(ys, xs);
        float val;
        if (s < 3) { float d = r - (float)s; val = expf(-d * d * (1.0f / 0.72f)); }
        else {
            int k = (s - 3) / 4 + 1; int rem = (s - 3) & 3;
            float r0 = (rem & 1) ? 2.0f : 1.0f; float d = r - r0;
            float ring = expf(-d * d * (1.0f / 0.72f));
            float ang = (float)k * th;
            val = ring * ((rem < 2) ? cosf(ang) : sinf(ang));
        }
        sb[q] = val;
    }
    __syncthreads();
    int idx = blockIdx.x * 256 + threadIdx.x;
    int ox = idx % WOUT; int tt = idx / WOUT; int oy = tt % WOUT; int n = tt / WOUT;
    const int plane = WOUT * WOUT;
    int aoff = (n * WOUT + oy) * WOUT + ox;
    float a0 = alpha[aoff], a1 = alpha[8 * plane + aoff];
    float rho = sqrtf(a0 * a0 + a1 * a1);
    float inv = 1.0f / (rho + 1e-8f);
    float c1 = a0 * inv, s1 = a1 * inv;
    float c2 = c1 * c1 - s1 * s1, s2 = 2.0f * s1 * c1;
    float c3 = c2 * c1 - s2 * s1, s3 = s2 * c1 + c2 * s1;
    int py = oy & 1, px = ox & 1;
    int iy0 = (oy >> 1) + 1, ix0 = (ox >> 1) + 1;
    float eb[9][9]; int off[9];
    #pragma unroll
    for (int t = 0; t < 9; ++t) {
        int ty = t / 3, tx = t % 3;
        int ky = py + 2 * ty, kx = px + 2 * tx;
        int iy = iy0 - ty, ix = ix0 - tx;
        bool v = (ky < 5) && (kx < 5) && (iy >= 0) && (iy < HIN) && (ix >= 0) && (ix < HIN);
        float m = v ? 1.0f : 0.0f;
        int ciy = min(max(iy, 0), HIN - 1), cix = min(max(ix, 0), HIN - 1);
        off[t] = ciy * HIN + cix;
        int bi_ = min(ky, 4) * 5 + min(kx, 4);
        eb[0][t] = sb[0 * 25 + bi_] * m;
        eb[1][t] = sb[1 * 25 + bi_] * m;
        eb[2][t] = sb[2 * 25 + bi_] * m;
        eb[3][t] = (sb[3 * 25 + bi_] * c1 + sb[5 * 25 + bi_] * s1) * m;
        eb[4][t] = (sb[4 * 25 + bi_] * c1 + sb[6 * 25 + bi_] * s1) * m;
        eb[5][t] = (sb[7 * 25 + bi_] * c2 + sb[9 * 25 + bi_] * s2) * m;
        eb[6][t] = (sb[8 * 25 + bi_] * c2 + sb[10 * 25 + bi_] * s2) * m;
        eb[7][t] = (sb[11 * 25 + bi_] * c3 + sb[13 * 25 + bi_] * s3) * m;
        eb[8][t] = (sb[12 * 25 + bi_] * c3 + sb[14 * 25 + bi_] * s3) * m;
    }
    float acc[NOUT];
    #pragma unroll
    for (int o = 0; o < NOUT; ++o) acc[o] = 0.0f;
    const float* xn = x + (size_t)n * NIN * HIN * HIN;
    for (int i = 0; i < NIN; ++i) {
        const float* xp = xn + (size_t)i * HIN * HIN;
        float tap[9];
        #pragma unroll
        for (int t = 0; t < 9; ++t) tap[t] = xp[off[t]];
        float G[9];
        #pragma unroll
        for (int b = 0; b < 9; ++b) {
            float s = 0.0f;
            #pragma unroll
            for (int t = 0; t < 9; ++t) s += eb[b][t] * tap[t];
            G[b] = s;
        }
        const float* wp = weights + i * 9;
        #pragma unroll
        for (int o = 0; o < NOUT; ++o) {
            float s = acc[o];
            #pragma unroll
            for (int b = 0; b < 9; ++b) s += wp[o * NIN * 9 + b] * G[b];
            acc[o] = s;
        }
    }
    #pragma unroll
    for (int o = 0; o < NOUT; ++o)
        out[((size_t)(n * NOUT + o) * WOUT + oy) * WOUT + ox] = rho * acc[o] + bias[o];
}

extern "C" void kernel_launch(void* const* d_in, const int* in_sizes, int n_in,
                              void* d_out, int out_size, void* d_ws, size_t ws_size,
                              hipStream_t stream) {
    const float* x       = (const float*)d_in[0];
    const float* alpha   = (const float*)d_in[1];
    const float* weights = (const float*)d_in[2];
    const float* bias    = (const float*)d_in[3];
    float* out = (float*)d_out;

    const size_t hoff = 32768;
    const size_t perb = HBATCH * 2;   // bytes per batch of h (bf16)
    int cb = 0;
    if (ws_size > hoff) cb = (int)((ws_size - hoff) / perb);
    if (cb > 8) cb = 8;

    if (cb < 1) {
        const int pixels = 8 * WOUT * WOUT;
        steered_convT<<<dim3(pixels / 256), 256, 0, stream>>>(x, alpha, weights, bias, out);
        return;
    }

    float* Wt = (float*)d_ws;
    ushort_t* h = (ushort_t*)((char*)d_ws + hoff);

    kprep_w<<<dim3(18), 256, 0, stream>>>(weights, Wt);
    kzero<<<dim3((cb * 772 + 255) / 256), 256, 0, stream>>>(h, cb);

    for (int n0 = 0; n0 < 8; n0 += cb) {
        int nb = 8 - n0; if (nb > cb) nb = cb;
        kA<<<dim3(144, nb), 256, 0, stream>>>(x, Wt, h, n0);
        kB<<<dim3(12, 24, nb), 256, 0, stream>>>(h, alpha, bias, out, n0);
    }
}

// Round 4
// 211.277 us; speedup vs baseline: 6.0318x; 4.7405x over previous
//
#include <hip/hip_runtime.h>

#define HIN 192
#define WOUT 384
#define NIN 32
#define NOUT 16
#define NSLOT 9
#define HP 194
#define HPLANE (HP * HP)                  // u32 elems per channel-pair plane (37636)
#define NPLANE 72                         // 144 bf16 channels / 2 per u32
#define HBATCH ((size_t)HPLANE * NPLANE)  // u32 elems per batch

__device__ __forceinline__ unsigned short f2bf(float f) {
    union { float f; unsigned int u; } v; v.f = f;
    unsigned int r = v.u + 0x7fffu + ((v.u >> 16) & 1u);   // RNE
    return (unsigned short)(r >> 16);
}
__device__ __forceinline__ float bfl(unsigned int u) { return __uint_as_float(u << 16); }
__device__ __forceinline__ float bfh(unsigned int u) { return __uint_as_float(u & 0xffff0000u); }

// ---- prep: Wt[c*256 + i*8 + j] = W[o][i][s],  m=c*8+j, s=m>>4, o=m&15 ----
__global__ __launch_bounds__(256) void kprep_w(const float* __restrict__ w, float* __restrict__ Wt) {
    int t = blockIdx.x * 256 + threadIdx.x;
    if (t >= NIN * NSLOT * NOUT) return;   // 4608
    int c = t >> 8, r = t & 255;
    int i = r >> 3, j = r & 7;
    int m = c * 8 + j;
    int s = m >> 4, o = m & 15;
    Wt[t] = w[(o * NIN + i) * NSLOT + s];
}

// ---- zero the 1-px halo border of every u32 plane ----
__global__ __launch_bounds__(256) void kzero(unsigned* __restrict__ hu, int nb) {
    int t = blockIdx.x * 256 + threadIdx.x;
    if (t >= nb * NPLANE * 772) return;
    int b = t / (NPLANE * 772);
    int j = (t / 772) % NPLANE;
    int r = t % 772;
    int iy, ix;
    if (r < 194)      { iy = 0;           ix = r; }
    else if (r < 388) { iy = 193;         ix = r - 194; }
    else if (r < 580) { iy = r - 388 + 1; ix = 0; }
    else              { iy = r - 580 + 1; ix = 193; }
    hu[(size_t)b * HBATCH + (size_t)j * HPLANE + iy * HP + ix] = 0u;
}

// ---- kA: channel mix at input resolution, bf16-pair planes ----
__global__ __launch_bounds__(256) void kA(const float* __restrict__ x,
                                          const float* __restrict__ Wt,
                                          unsigned* __restrict__ hu, int n0) {
    const int b = blockIdx.y;
    const int n = n0 + b;
    const int px = blockIdx.x * 256 + threadIdx.x;   // 0..36863
    const int iy = px / HIN, ix = px % HIN;
    const float* xp = x + (size_t)n * NIN * HIN * HIN + px;
    float xv[NIN];
    #pragma unroll
    for (int i = 0; i < NIN; ++i) xv[i] = xp[(size_t)i * HIN * HIN];
    const unsigned pos = (iy + 1) * HP + (ix + 1);
    unsigned* hb = hu + (size_t)b * HBATCH;
    #pragma unroll 1
    for (int c = 0; c < 18; ++c) {
        const float* wc = Wt + c * 256;              // uniform -> scalar loads
        float a[8];
        #pragma unroll
        for (int j = 0; j < 8; ++j) a[j] = 0.0f;
        #pragma unroll
        for (int i = 0; i < NIN; ++i) {
            const float xi = xv[i];
            #pragma unroll
            for (int j = 0; j < 8; ++j) a[j] = fmaf(wc[i * 8 + j], xi, a[j]);
        }
        #pragma unroll
        for (int t = 0; t < 4; ++t) {
            unsigned v = (unsigned)f2bf(a[2 * t]) | ((unsigned)f2bf(a[2 * t + 1]) << 16);
            hb[(size_t)(c * 4 + t) * HPLANE + pos] = v;
        }
    }
}

// ---- kB body: one wave = one parity; one thread = one site, 16 channels ----
template<int PY, int PX>
__device__ __forceinline__ void kb_body(const unsigned* __restrict__ hb,
                                        const float* __restrict__ alpha,
                                        const float* __restrict__ bias,
                                        float (&stage)[2][16][128],
                                        const float2 (&Cb)[NSLOT][25],
                                        int n, int Y, int X, int lane) {
    const int oy = 2 * Y + PY, ox = 2 * X + PX;
    const int aoff = (n * WOUT + oy) * WOUT + ox;
    const float a0 = alpha[aoff];
    const float a1 = alpha[(size_t)8 * WOUT * WOUT + aoff];
    const float rr = sqrtf(a0 * a0 + a1 * a1);
    const float inv = 1.0f / (rr + 1e-8f);
    const float c1 = a0 * inv, s1 = a1 * inv;
    const float c2 = c1 * c1 - s1 * s1, s2 = 2.0f * c1 * s1;
    const float c3 = c2 * c1 - s2 * s1, s3 = s2 * c1 + c2 * s1;

    float acc[16];
    #pragma unroll
    for (int o = 0; o < 16; ++o) acc[o] = 0.0f;

    #pragma unroll 1
    for (int ty = 0; ty < 3 - PY; ++ty) {
        const int piy = Y + 2 - ty;
        #pragma unroll 1
        for (int tx = 0; tx < 3 - PX; ++tx) {
            const int pix = X + 2 - tx;
            const int bi = (PY + 2 * ty) * 5 + (PX + 2 * tx);
            const unsigned pos = (unsigned)(piy * HP + pix);
            #pragma unroll
            for (int s = 0; s < NSLOT; ++s) {
                const float2 C = Cb[s][bi];
                float eb;
                if      (s < 3) eb = C.x;
                else if (s < 5) eb = C.x * c1 + C.y * s1;
                else if (s < 7) eb = C.x * c2 + C.y * s2;
                else            eb = C.x * c3 + C.y * s3;
                #pragma unroll
                for (int jj = 0; jj < 8; ++jj) {
                    const unsigned v = hb[(unsigned)(s * 8 + jj) * (unsigned)HPLANE + pos];
                    acc[2 * jj]     = fmaf(eb, bfl(v), acc[2 * jj]);
                    acc[2 * jj + 1] = fmaf(eb, bfh(v), acc[2 * jj + 1]);
                }
            }
        }
    }

    #pragma unroll
    for (int o = 0; o < 16; ++o)
        stage[PY][o][2 * lane + PX] = rr * acc[o] + bias[o];
}

__global__ __launch_bounds__(256, 3) void kB(const unsigned* __restrict__ hu,
                                             const float* __restrict__ alpha,
                                             const float* __restrict__ bias,
                                             float* __restrict__ out, int n0) {
    __shared__ float2 Cb[NSLOT][25];
    __shared__ float stage[2][16][128];
    {
        const int q = threadIdx.x;
        if (q < NSLOT * 25) {
            int s = q / 25, p = q % 25;
            int ky = p / 5, kx = p % 5;
            float ys = (float)(ky - 2), xs = (float)(kx - 2);
            float r = sqrtf(xs * xs + ys * ys);
            float th = atan2f(ys, xs);
            float cr, ci;
            if (s < 3) {
                float d = r - (float)s;
                cr = expf(-d * d * (1.0f / 0.72f));
                ci = 0.0f;
            } else {
                int k = (s - 3) / 2 + 1;
                float r0 = ((s - 3) & 1) ? 2.0f : 1.0f;
                float d = r - r0;
                float ring = expf(-d * d * (1.0f / 0.72f));
                float a = (float)k * th;
                cr = ring * cosf(a);
                ci = ring * sinf(a);
            }
            Cb[s][p] = make_float2(cr, ci);
        }
    }
    __syncthreads();

    const int b = blockIdx.z;
    const int n = n0 + b;
    const int Y = blockIdx.y;                 // site row 0..191
    const int lane = threadIdx.x & 63;
    const int wv = threadIdx.x >> 6;          // wave id = parity
    const int X = blockIdx.x * 64 + lane;     // site col

    const unsigned* hb = hu + (size_t)b * HBATCH;
    if      (wv == 0) kb_body<0, 0>(hb, alpha, bias, stage, Cb, n, Y, X, lane);
    else if (wv == 1) kb_body<0, 1>(hb, alpha, bias, stage, Cb, n, Y, X, lane);
    else if (wv == 2) kb_body<1, 0>(hb, alpha, bias, stage, Cb, n, Y, X, lane);
    else              kb_body<1, 1>(hb, alpha, bias, stage, Cb, n, Y, X, lane);

    __syncthreads();

    // cooperative coalesced store: 2 oy-rows x 16 channels x 128 px
    #pragma unroll
    for (int q = 0; q < 16; ++q) {
        const int f = q * 256 + threadIdx.x;
        const int row = f >> 7, col = f & 127;
        const int py = row >> 4, o = row & 15;
        out[(((size_t)n * NOUT + o) * WOUT + (2 * Y + py)) * WOUT + blockIdx.x * 128 + col]
            = stage[py][o][col];
    }
}

// ---- fallback: proven round-1 monolithic kernel ----
__global__ __launch_bounds__(256) void steered_convT(
    const float* __restrict__ x, const float* __restrict__ alpha,
    const float* __restrict__ weights, const float* __restrict__ bias,
    float* __restrict__ out) {
    __shared__ float sb[15 * 25];
    for (int q = threadIdx.x; q < 375; q += 256) {
        int s = q / 25, p = q % 25;
        int ky = p / 5, kx = p % 5;
        float ys = (float)(ky - 2), xs = (float)(kx - 2);
        float r = sqrtf(xs * xs + ys * ys);
        float th = atan2f(ys, xs);
        float val;
        if (s < 3) { float d = r - (float)s; val = expf(-d * d * (1.0f / 0.72f)); }
        else {
            int k = (s - 3) / 4 + 1; int rem = (s - 3) & 3;
            float r0 = (rem & 1) ? 2.0f : 1.0f; float d = r - r0;
            float ring = expf(-d * d * (1.0f / 0.72f));
            float ang = (float)k * th;
            val = ring * ((rem < 2) ? cosf(ang) : sinf(ang));
        }
        sb[q] = val;
    }
    __syncthreads();
    int idx = blockIdx.x * 256 + threadIdx.x;
    int ox = idx % WOUT; int tt = idx / WOUT; int oy = tt % WOUT; int n = tt / WOUT;
    const int plane = WOUT * WOUT;
    int aoff = (n * WOUT + oy) * WOUT + ox;
    float a0 = alpha[aoff], a1 = alpha[8 * plane + aoff];
    float rho = sqrtf(a0 * a0 + a1 * a1);
    float inv = 1.0f / (rho + 1e-8f);
    float c1 = a0 * inv, s1 = a1 * inv;
    float c2 = c1 * c1 - s1 * s1, s2 = 2.0f * s1 * c1;
    float c3 = c2 * c1 - s2 * s1, s3 = s2 * c1 + c2 * s1;
    int py = oy & 1, px = ox & 1;
    int iy0 = (oy >> 1) + 1, ix0 = (ox >> 1) + 1;
    float eb[9][9]; int off[9];
    #pragma unroll
    for (int t = 0; t < 9; ++t) {
        int ty = t / 3, tx = t % 3;
        int ky = py + 2 * ty, kx = px + 2 * tx;
        int iy = iy0 - ty, ix = ix0 - tx;
        bool v = (ky < 5) && (kx < 5) && (iy >= 0) && (iy < HIN) && (ix >= 0) && (ix < HIN);
        float m = v ? 1.0f : 0.0f;
        int ciy = min(max(iy, 0), HIN - 1), cix = min(max(ix, 0), HIN - 1);
        off[t] = ciy * HIN + cix;
        int bi_ = min(ky, 4) * 5 + min(kx, 4);
        eb[0][t] = sb[0 * 25 + bi_] * m;
        eb[1][t] = sb[1 * 25 + bi_] * m;
        eb[2][t] = sb[2 * 25 + bi_] * m;
        eb[3][t] = (sb[3 * 25 + bi_] * c1 + sb[5 * 25 + bi_] * s1) * m;
        eb[4][t] = (sb[4 * 25 + bi_] * c1 + sb[6 * 25 + bi_] * s1) * m;
        eb[5][t] = (sb[7 * 25 + bi_] * c2 + sb[9 * 25 + bi_] * s2) * m;
        eb[6][t] = (sb[8 * 25 + bi_] * c2 + sb[10 * 25 + bi_] * s2) * m;
        eb[7][t] = (sb[11 * 25 + bi_] * c3 + sb[13 * 25 + bi_] * s3) * m;
        eb[8][t] = (sb[12 * 25 + bi_] * c3 + sb[14 * 25 + bi_] * s3) * m;
    }
    float acc[NOUT];
    #pragma unroll
    for (int o = 0; o < NOUT; ++o) acc[o] = 0.0f;
    const float* xn = x + (size_t)n * NIN * HIN * HIN;
    for (int i = 0; i < NIN; ++i) {
        const float* xp = xn + (size_t)i * HIN * HIN;
        float tap[9];
        #pragma unroll
        for (int t = 0; t < 9; ++t) tap[t] = xp[off[t]];
        float G[9];
        #pragma unroll
        for (int b = 0; b < 9; ++b) {
            float s = 0.0f;
            #pragma unroll
            for (int t = 0; t < 9; ++t) s += eb[b][t] * tap[t];
            G[b] = s;
        }
        const float* wp = weights + i * 9;
        #pragma unroll
        for (int o = 0; o < NOUT; ++o) {
            float s = acc[o];
            #pragma unroll
            for (int b = 0; b < 9; ++b) s += wp[o * NIN * 9 + b] * G[b];
            acc[o] = s;
        }
    }
    #pragma unroll
    for (int o = 0; o < NOUT; ++o)
        out[((size_t)(n * NOUT + o) * WOUT + oy) * WOUT + ox] = rho * acc[o] + bias[o];
}

extern "C" void kernel_launch(void* const* d_in, const int* in_sizes, int n_in,
                              void* d_out, int out_size, void* d_ws, size_t ws_size,
                              hipStream_t stream) {
    const float* x       = (const float*)d_in[0];
    const float* alpha   = (const float*)d_in[1];
    const float* weights = (const float*)d_in[2];
    const float* bias    = (const float*)d_in[3];
    float* out = (float*)d_out;

    const size_t hoff = 32768;
    const size_t perb = HBATCH * 4;          // bytes per batch of h (u32 planes)
    int cb = 0;
    if (ws_size > hoff) cb = (int)((ws_size - hoff) / perb);
    if (cb > 8) cb = 8;

    if (cb < 1) {
        const int pixels = 8 * WOUT * WOUT;
        steered_convT<<<dim3(pixels / 256), 256, 0, stream>>>(x, alpha, weights, bias, out);
        return;
    }

    float* Wt = (float*)d_ws;
    unsigned* hu = (unsigned*)((char*)d_ws + hoff);

    kprep_w<<<dim3(18), 256, 0, stream>>>(weights, Wt);

    for (int n0 = 0; n0 < 8; n0 += cb) {
        int nb = 8 - n0; if (nb > cb) nb = cb;
        kzero<<<dim3((nb * NPLANE * 772 + 255) / 256), 256, 0, stream>>>(hu, nb);
        kA<<<dim3(144, nb), 256, 0, stream>>>(x, Wt, hu, n0);
        kB<<<dim3(3, 192, nb), 256, 0, stream>>>(hu, alpha, bias, out, n0);
    }
}